// Round 14
// baseline (686.911 us; speedup 1.0000x reference)
//
#include <hip/hip_runtime.h>
#include <hip/hip_bf16.h>

typedef __hip_bfloat16 bf16;
typedef unsigned int u32;
typedef __attribute__((ext_vector_type(8))) short bf16x8;
typedef __attribute__((ext_vector_type(4))) float f32x4;

#define HWSZ 65536u   // 256*256

__device__ __forceinline__ float b2f_lo(u32 w){ return __uint_as_float(w << 16); }
__device__ __forceinline__ float b2f_hi(u32 w){ return __uint_as_float(w & 0xffff0000u); }
__device__ __forceinline__ float b2f(bf16 v){ return __bfloat162float(v); }
__device__ __forceinline__ bf16 f2b(float v){ return __float2bfloat16(v); }

__device__ __forceinline__ u32 f2bbits(float f){
  u32 x = __float_as_uint(f);
  return ((x + 0x7fffu + ((x >> 16) & 1u)) >> 16) & 0xffffu;  // RNE
}

union ABu { u32 u[4]; bf16x8 v; uint4 q; };

// xs unit index: stride 193 units/c8 (193 mod 8 == 1 -> the 8 c8 groups occupy
// 8 distinct bank-quads; b128 reads are <=2-way aliased = free). Linear in px.
__device__ __forceinline__ int xsw(int c8, int px){
  return c8 * 193 + px;
}

// ---------------- K0: fused conv weights W3[192][576]: W3[o][tap*64+c] = wdw[o,tap]*wq[o,c]
__global__ __launch_bounds__(256) void k0_w3(
    const float* __restrict__ wq, const float* __restrict__ wdw, bf16* __restrict__ w3){
  int idx = blockIdx.x * 256 + threadIdx.x;       // 432*256 = 110592 = 192*576
  int och = idx / 576, r = idx - och * 576;
  int tap = r >> 6, c = r & 63;
  w3[idx] = f2b(wdw[och * 9 + tap] * wq[och * 64 + c]);
}

// ---------------- K12 (v9 = v7 + conflict-free stride): pointwise+depthwise as ONE
// GEMM vs W3, direct tok store. 256 threads (4 waves), block = (b, yt 16-row, xt 8-col).
// xs: x bf16 [c8=8][px 180 of 193] 16B units. 1 barrier, no qs.
__global__ __launch_bounds__(256) void k12_fused(
    const float* __restrict__ x, const bf16* __restrict__ w3, bf16* __restrict__ tok){
  __shared__ uint4 xs[8 * 193];                   // 24.7 KB
  int t = threadIdx.x;
  int lane = t & 63, w = t >> 6;                  // 4 waves
  int r16 = lane & 15, g4 = lane >> 4;

  u32 n = blockIdx.x;
  u32 bid = (n & 7u) * 1024u + (n >> 3);          // XCD swizzle (8192 = 8*1024)
  u32 xt = bid & 31u, yt = (bid >> 5) & 15u, b = bid >> 9;
  int y0 = (int)yt * 16, x0 = (int)xt * 8;
  const float* xb = x + (size_t)b * 64 * HWSZ;

  // ---- stage x: 576 units = (c8, rr in [0,18), jq in [0,4)); unit = 2 ch x 10 cols
  for (int u = t; u < 576; u += 256){
    int jq = u & 3, rr = (u >> 2) % 18, c8 = u / 72;
    int yy = y0 - 1 + rr;
    float va[2][10];
    if ((u32)yy < 256u){
      #pragma unroll
      for (int jc = 0; jc < 2; jc++){
        const float* p = xb + (size_t)(c8 * 8 + jq * 2 + jc) * HWSZ + ((size_t)yy << 8);
        float4 A  = *(const float4*)(p + x0);     // 16B-aligned (x0 % 8 == 0)
        float4 Bq = *(const float4*)(p + x0 + 4);
        va[jc][0] = (x0 > 0) ? p[x0 - 1] : 0.f;
        va[jc][1] = A.x;  va[jc][2] = A.y;  va[jc][3] = A.z;  va[jc][4] = A.w;
        va[jc][5] = Bq.x; va[jc][6] = Bq.y; va[jc][7] = Bq.z; va[jc][8] = Bq.w;
        va[jc][9] = (x0 + 8 < 256) ? p[x0 + 8] : 0.f;
      }
    } else {
      #pragma unroll
      for (int jc = 0; jc < 2; jc++)
        #pragma unroll
        for (int e = 0; e < 10; e++) va[jc][e] = 0.f;
    }
    #pragma unroll
    for (int e = 0; e < 10; e++){
      u32 wv = f2bbits(va[0][e]) | (f2bbits(va[1][e]) << 16);
      ((u32*)&xs[xsw(c8, rr * 10 + e)])[jq] = wv;
    }
  }
  if (t < 96){                                    // zero-pad px 180..191
    int c8 = t / 12, px = 180 + (t % 12);
    xs[xsw(c8, px)] = make_uint4(0u, 0u, 0u, 0u);
  }
  __syncthreads();

  // ---- GEMM: D[och=192][px=128] over K=576 (9 taps x 64 ch)
  f32x4 acc[3][8];
  #pragma unroll
  for (int m = 0; m < 3; m++)
    #pragma unroll
    for (int nt = 0; nt < 8; nt++) acc[m][nt] = (f32x4){0.f, 0.f, 0.f, 0.f};

  // W3 row bases for this lane's 3 och rows (och = 64*m + 16*w + r16)
  const bf16* w3r0 = w3 + (size_t)(16 * w + r16) * 576 + g4 * 8;
  const bf16* w3r1 = w3r0 + (size_t)64 * 576;
  const bf16* w3r2 = w3r1 + (size_t)64 * 576;

  int orow = r16 >> 3, ocol = (r16 & 7) + 1;      // output row-in-pair, input col

  #pragma unroll 2
  for (int ks = 0; ks < 18; ks++){
    int tap = ks >> 1;
    int dy = tap / 3, dx = tap % 3;               // input offset
    ABu a0, a1, a2;
    a0.q = *(const uint4*)(w3r0 + ks * 32);
    a1.q = *(const uint4*)(w3r1 + ks * 32);
    a2.q = *(const uint4*)(w3r2 + ks * 32);
    int c8 = (ks & 1) * 4 + g4;
    int prow = orow + dy;                         // input row = 2*nt + orow + dy
    int pcol = ocol + dx - 1;
    #pragma unroll
    for (int nt = 0; nt < 8; nt++){
      int px = (2 * nt + prow) * 10 + pcol;
      uint4 uq = xs[xsw(c8, px)];
      bf16x8 bv = *reinterpret_cast<bf16x8*>(&uq);
      acc[0][nt] = __builtin_amdgcn_mfma_f32_16x16x32_bf16(a0.v, bv, acc[0][nt], 0, 0, 0);
      acc[1][nt] = __builtin_amdgcn_mfma_f32_16x16x32_bf16(a1.v, bv, acc[1][nt], 0, 0, 0);
      acc[2][nt] = __builtin_amdgcn_mfma_f32_16x16x32_bf16(a2.v, bv, acc[2][nt], 0, 0, 0);
    }
  }

  // ---- store: lane holds 4 ch (och = 64m + 16w + g4*4 + r) of pixel px(nt, r16)
  u32 win = (yt >> 1) * 8u + (xt >> 2);
  int choff = w * 16 + g4 * 4;
  int p1 = (int)(xt & 3u) * 8 + (r16 & 7);
  #pragma unroll
  for (int m = 0; m < 3; m++){
    #pragma unroll
    for (int nt = 0; nt < 8; nt++){
      int row = 2 * nt + orow;
      int h = (int)(yt & 1u) * 4 + (row >> 2);
      int p0r = row & 3;
      size_t off = (((((size_t)m * 16 + b) * 8 + h) * 64 + win) * 8192)
                 + (size_t)p0r * 2048 + (size_t)p1 * 64 + choff;
      u32 lo = f2bbits(acc[m][nt][0]) | (f2bbits(acc[m][nt][1]) << 16);
      u32 hi = f2bbits(acc[m][nt][2]) | (f2bbits(acc[m][nt][3]) << 16);
      *(uint2*)(tok + off) = make_uint2(lo, hi);
    }
  }
}

// ---------------- K3 (MFMA): sim partials over d-quarter -> sim4[part][b][h][64][64]
__global__ __launch_bounds__(256) void k3_sim(
    const bf16* __restrict__ tok, float* __restrict__ sim4){
  __shared__ short qs[64 * 72];
  __shared__ short ks[64 * 72];
  int t = threadIdx.x;
  int lane = t & 63, w = t >> 6;
  int r16 = lane & 15, g4 = lane >> 4;
  u32 bid = blockIdx.x;
  u32 part = bid & 3u, h = (bid >> 2) & 7u, b = bid >> 5;
  const bf16* qb = tok + ((size_t)(((0 * 16 + b) * 8 + h) * 64)) * 8192 + part * 2048;
  const bf16* kb = tok + ((size_t)(((1 * 16 + b) * 8 + h) * 64)) * 8192 + part * 2048;

  int stok = t >> 2, soct = t & 3;

  f32x4 acc[4];
  #pragma unroll
  for (int jt = 0; jt < 4; jt++) acc[jt] = (f32x4){0.f,0.f,0.f,0.f};

  for (int s = 0; s < 32; s++){
    int d0 = s * 64;
    __syncthreads();
    {
      uint4 q0 = *(const uint4*)(qb + (size_t)stok * 8192 + d0 + soct * 8);
      uint4 q1 = *(const uint4*)(qb + (size_t)stok * 8192 + d0 + soct * 8 + 32);
      uint4 k0 = *(const uint4*)(kb + (size_t)stok * 8192 + d0 + soct * 8);
      uint4 k1 = *(const uint4*)(kb + (size_t)stok * 8192 + d0 + soct * 8 + 32);
      *(uint4*)&qs[stok * 72 + soct * 8]      = q0;
      *(uint4*)&qs[stok * 72 + soct * 8 + 32] = q1;
      *(uint4*)&ks[stok * 72 + soct * 8]      = k0;
      *(uint4*)&ks[stok * 72 + soct * 8 + 32] = k1;
    }
    __syncthreads();
    #pragma unroll
    for (int kt = 0; kt < 2; kt++){
      bf16x8 a = *(const bf16x8*)&qs[(w * 16 + r16) * 72 + kt * 32 + g4 * 8];
      #pragma unroll
      for (int jt = 0; jt < 4; jt++){
        bf16x8 bb = *(const bf16x8*)&ks[(jt * 16 + r16) * 72 + kt * 32 + g4 * 8];
        acc[jt] = __builtin_amdgcn_mfma_f32_16x16x32_bf16(a, bb, acc[jt], 0, 0, 0);
      }
    }
  }

  float* sp = sim4 + ((((size_t)part * 16 + b) * 8 + h) * 64) * 64;
  #pragma unroll
  for (int jt = 0; jt < 4; jt++)
    #pragma unroll
    for (int r = 0; r < 4; r++)
      sp[(w * 16 + g4 * 4 + r) * 64 + jt * 16 + r16] = acc[jt][r];
}

// ---------------- K4: combine partials, scale, +pos_emb, softmax
__global__ __launch_bounds__(64) void k4_softmax(
    const float* __restrict__ sim4, const float* __restrict__ pos, float* __restrict__ attn){
  int j = threadIdx.x;
  u32 bid = blockIdx.x;
  u32 i = bid & 63u, h = (bid >> 6) & 7u, b = bid >> 9;
  size_t o = (((size_t)b * 8 + h) * 64 + i) * 64 + j;
  const size_t pstride = (size_t)16 * 8 * 64 * 64;
  float s = sim4[o] + sim4[o + pstride] + sim4[o + 2 * pstride] + sim4[o + 3 * pstride];
  s = s * 0.011048543456039806f + pos[(((size_t)h * 64) + i) * 64 + j];
  float m = s;
  #pragma unroll
  for (int off = 32; off; off >>= 1) m = fmaxf(m, __shfl_xor(m, off));
  float e = __expf(s - m);
  float sum = e;
  #pragma unroll
  for (int off = 32; off; off >>= 1) sum += __shfl_xor(sum, off);
  attn[o] = e / sum;
}

// ---------------- K5 (MFMA): otok[i,d] = sum_j attn[i,j] * V[j,d]
__global__ __launch_bounds__(256) void k5_av(
    const bf16* __restrict__ tok, const float* __restrict__ attn, bf16* __restrict__ otok){
  __shared__ short vt[4][64 * 72];
  int t = threadIdx.x;
  int lane = t & 63, w = t >> 6;
  int r16 = lane & 15, g4 = lane >> 4;
  u32 bid = blockIdx.x;
  u32 q = bid & 3u, h = (bid >> 2) & 7u, b = bid >> 5;
  const bf16* vb = tok + ((size_t)(((2 * 16 + b) * 8 + h) * 64)) * 8192;
  const float* ab = attn + (((size_t)b * 8 + h) * 64) * 64;
  bf16* ob = otok + (((size_t)b * 8 + h) * 64) * 8192;

  bf16x8 af[4][2];
  #pragma unroll
  for (int it = 0; it < 4; it++)
    #pragma unroll
    for (int kt = 0; kt < 2; kt++){
      const float* ar = ab + (it * 16 + r16) * 64 + kt * 32 + g4 * 8;
      ABu pk;
      #pragma unroll
      for (int j = 0; j < 4; j++)
        pk.u[j] = f2bbits(ar[2 * j]) | (f2bbits(ar[2 * j + 1]) << 16);
      af[it][kt] = pk.v;
    }

  short* vtw = vt[w];
  for (int s = 0; s < 8; s++){
    int d0 = (int)q * 2048 + s * 256 + w * 64;
    uint4 ld[8];
    const bf16* vp = vb + (size_t)lane * 8192 + d0;
    #pragma unroll
    for (int u = 0; u < 8; u++) ld[u] = *(const uint4*)(vp + u * 8);
    #pragma unroll
    for (int u = 0; u < 8; u++){
      const u32* wd = (const u32*)&ld[u];
      #pragma unroll
      for (int e = 0; e < 4; e++){
        int d = u * 8 + e * 2;
        vtw[d * 72 + lane]       = (short)(wd[e] & 0xffffu);
        vtw[(d + 1) * 72 + lane] = (short)(wd[e] >> 16);
      }
    }
    #pragma unroll
    for (int dt = 0; dt < 4; dt++){
      bf16x8 b0 = *(const bf16x8*)&vtw[(dt * 16 + r16) * 72 + 0 * 32 + g4 * 8];
      bf16x8 b1 = *(const bf16x8*)&vtw[(dt * 16 + r16) * 72 + 1 * 32 + g4 * 8];
      #pragma unroll
      for (int it = 0; it < 4; it++){
        f32x4 acc = (f32x4){0.f,0.f,0.f,0.f};
        acc = __builtin_amdgcn_mfma_f32_16x16x32_bf16(af[it][0], b0, acc, 0, 0, 0);
        acc = __builtin_amdgcn_mfma_f32_16x16x32_bf16(af[it][1], b1, acc, 0, 0, 0);
        #pragma unroll
        for (int r = 0; r < 4; r++)
          ob[(size_t)(it * 16 + g4 * 4 + r) * 8192 + d0 + dt * 16 + r16] = f2b(acc[r]);
      }
    }
  }
}

// ---------------- K6 (MFMA): out[b,64,HW] fp32 = Wp[64,64] x OT[64,HW] + bias
__global__ __launch_bounds__(256) void k6_mfma(
    const bf16* __restrict__ otok, const float* __restrict__ wp,
    const float* __restrict__ bp, float* __restrict__ out){
  __shared__ uint4 xs[1024];
  int t = threadIdx.x;
  int lane = t & 63, w = t >> 6;
  u32 pix0 = blockIdx.x * 128u;
  u32 b = pix0 >> 16, hw0 = pix0 & 65535u;
  int y = (int)(hw0 >> 8);
  int p0 = y & 31, h = p0 >> 2, prow = (p0 & 3) * 2048;
  int iy = (y >> 5) << 3;

  {
    int pix = t & 127, half = t >> 7;
    int xx = (int)(hw0 & 255u) + pix;
    int i = iy + (xx >> 5), p1 = xx & 31;
    const bf16* ip = otok + ((((size_t)b * 8 + h) * 64 + i)) * 8192 + prow + p1 * 64;
    #pragma unroll
    for (int g = 0; g < 4; g++){
      int c8 = half * 4 + g;
      xs[c8 * 128 + pix] = *(const uint4*)(ip + c8 * 8);
    }
  }

  int r16 = lane & 15, g4 = lane >> 4;
  bf16x8 af[2];
  int och = w * 16 + r16;
  #pragma unroll
  for (int kt = 0; kt < 2; kt++){
    const float* wr = wp + och * 64 + kt * 32 + g4 * 8;
    ABu pk;
    #pragma unroll
    for (int j = 0; j < 4; j++)
      pk.u[j] = f2bbits(wr[2 * j]) | (f2bbits(wr[2 * j + 1]) << 16);
    af[kt] = pk.v;
  }
  float bias[4];
  #pragma unroll
  for (int r = 0; r < 4; r++) bias[r] = bp[w * 16 + g4 * 4 + r];
  __syncthreads();

  f32x4 acc[8];
  #pragma unroll
  for (int pt = 0; pt < 8; pt++) acc[pt] = (f32x4){bias[0], bias[1], bias[2], bias[3]};

  #pragma unroll
  for (int pt = 0; pt < 8; pt++){
    uint4 u0 = xs[(0 * 4 + g4) * 128 + pt * 16 + r16];
    uint4 u1 = xs[(1 * 4 + g4) * 128 + pt * 16 + r16];
    bf16x8 b0 = *reinterpret_cast<bf16x8*>(&u0);
    bf16x8 b1 = *reinterpret_cast<bf16x8*>(&u1);
    acc[pt] = __builtin_amdgcn_mfma_f32_16x16x32_bf16(af[0], b0, acc[pt], 0, 0, 0);
    acc[pt] = __builtin_amdgcn_mfma_f32_16x16x32_bf16(af[1], b1, acc[pt], 0, 0, 0);
  }

  float* op = out + (size_t)b * 64 * HWSZ + hw0;
  int ochb = w * 16 + g4 * 4;
  #pragma unroll
  for (int pt = 0; pt < 8; pt++)
    #pragma unroll
    for (int r = 0; r < 4; r++)
      op[(size_t)(ochb + r) * HWSZ + pt * 16 + r16] = acc[pt][r];
}

extern "C" void kernel_launch(void* const* d_in, const int* in_sizes, int n_in,
                              void* d_out, int out_size, void* d_ws, size_t ws_size,
                              hipStream_t stream){
  const float* x   = (const float*)d_in[0];
  const float* wq  = (const float*)d_in[1];
  const float* wdw = (const float*)d_in[2];
  const float* wp  = (const float*)d_in[3];
  const float* bp  = (const float*)d_in[4];
  const float* pos = (const float*)d_in[5];
  float* out = (float*)d_out;
  (void)in_sizes; (void)n_in; (void)out_size; (void)ws_size;

  char* ws = (char*)d_ws;
  bf16*  tok  = (bf16*)(ws + 402653184u);
  bf16*  otok = (bf16*)ws;
  float* sim4 = (float*)(ws + 134217728u);
  float* attn = (float*)(ws + 142606336u);
  bf16*  w3   = (bf16*)(ws + 144703488u);   // 221,184 B

  k0_w3<<<dim3(432), dim3(256), 0, stream>>>(wq, wdw, w3);
  k12_fused<<<dim3(8192), dim3(256), 0, stream>>>(x, w3, tok);
  k3_sim<<<dim3(512),   dim3(256), 0, stream>>>(tok, sim4);
  k4_softmax<<<dim3(8192), dim3(64), 0, stream>>>(sim4, pos, attn);
  k5_av<<<dim3(512),  dim3(256), 0, stream>>>(tok, attn, otok);
  k6_mfma<<<dim3(8192), dim3(256), 0, stream>>>(otok, wp, bp, out);
}